// Round 14
// baseline (176.860 us; speedup 1.0000x reference)
//
#include <hip/hip_runtime.h>
#include <hip/hip_fp16.h>
#include <hip/hip_bf16.h>
#include <math.h>

#define LEAKY 0.01f

typedef __attribute__((ext_vector_type(8))) short short8v;
typedef __attribute__((ext_vector_type(4))) float f32x4;

__device__ inline float fast_tanh(float x) {
    float e2 = __expf(2.0f * x);
    return 1.0f - 2.0f * __builtin_amdgcn_rcpf(e2 + 1.0f);
}

__device__ inline float2 h2f(uint w) {
    __half2 h = *reinterpret_cast<__half2*>(&w);
    return __half22float2(h);
}

__device__ inline short f2bf(float f) {
    __hip_bfloat16 h = __float2bfloat16(f);
    short s;
    __builtin_memcpy(&s, &h, 2);
    return s;
}

// ---------------------------------------------------------------------------
// Kernel 1 (MFMA, 64 rows/block): [U||V] = z @ Wcat + bcat.
// 1563 blocks x 4 waves; wave w owns rows blk*64 + w*16 (one 16x64 C tile).
// LDS: Wcat bf16 [col][k] (9.2 KB) + per-wave 16x72 fp16 staging (9.2 KB)
// -> high residency. W1 staged with LINEAR (coalesced) global reads,
// transpose happens on the LDS-write side.
//   A frag: lane l: row (l&15), k = kk*32 + (l>>4)*8 .. +7  (from global)
//   B frag: col = ni*16 + (l&15), same k pattern (from LDS)
//   C/D  : col = l&15, row = (l>>4)*4 + reg   [verified m89/m91]
// ---------------------------------------------------------------------------
__global__ __launch_bounds__(256) void node_proj_mfma64(
    const float* __restrict__ z, const float* __restrict__ W1,
    const float* __restrict__ b1, __half* __restrict__ U, __half* __restrict__ V,
    int N)
{
    __shared__ short w1l[64 * 72];        // 9.2 KB: Wcat bf16, [col][k] stride 72
    __shared__ __half st[4][16 * 72];     // 9.2 KB: per-wave C staging

    int tid = threadIdx.x;
    int w = tid >> 6;
    int l = tid & 63;

    // ---- stage Wcat: linear coalesced read of W1 (4096 floats), scatter to LDS ----
    for (int i = tid; i < 4096; i += 256) {
        float wv = W1[i];
        int ii = i & 2047;
        int k = ii >> 5;
        int j = (i < 2048) ? (ii & 31) : (32 + (ii & 31));
        w1l[j * 72 + k] = f2bf(wv);
    }
    __syncthreads();

    // ---- A fragment straight from global (guarded), cvt f32->bf16 ----
    const float4* z4 = reinterpret_cast<const float4*>(z);
    int rbase = blockIdx.x * 64 + w * 16 + (l & 15);
    int koff = (l >> 4) * 8;
    bool ok = rbase < N;
    size_t rowoff = (size_t)(ok ? rbase : 0) * 16;
    short8v afr[2];
    #pragma unroll
    for (int kk = 0; kk < 2; ++kk) {
        int kq = kk * 8 + (l >> 4) * 2;
        float4 p0 = z4[rowoff + kq];
        float4 p1 = z4[rowoff + kq + 1];
        if (!ok) { p0 = make_float4(0, 0, 0, 0); p1 = make_float4(0, 0, 0, 0); }
        short8v f;
        f[0] = f2bf(p0.x); f[1] = f2bf(p0.y); f[2] = f2bf(p0.z); f[3] = f2bf(p0.w);
        f[4] = f2bf(p1.x); f[5] = f2bf(p1.y); f[6] = f2bf(p1.z); f[7] = f2bf(p1.w);
        afr[kk] = f;
    }

    // ---- MFMA: acc[ni] over K=64 (2 steps of 32) ----
    f32x4 acc[4];
    #pragma unroll
    for (int ni = 0; ni < 4; ++ni) acc[ni] = (f32x4){0.0f, 0.0f, 0.0f, 0.0f};

    #pragma unroll
    for (int kk = 0; kk < 2; ++kk) {
        #pragma unroll
        for (int ni = 0; ni < 4; ++ni) {
            int col = ni * 16 + (l & 15);
            short8v bfr = *reinterpret_cast<const short8v*>(&w1l[col * 72 + kk * 32 + koff]);
            acc[ni] = __builtin_amdgcn_mfma_f32_16x16x32_bf16(afr[kk], bfr, acc[ni], 0, 0, 0);
        }
    }

    // ---- bias + fp16 pack into per-wave LDS staging ----
    __half* stw = &st[w][0];
    #pragma unroll
    for (int ni = 0; ni < 4; ++ni) {
        int col = ni * 16 + (l & 15);
        float bc = (col < 32) ? b1[col] : 0.0f;
        #pragma unroll
        for (int r = 0; r < 4; ++r) {
            int row = (l >> 4) * 4 + r;
            stw[row * 72 + col] = __float2half(acc[ni][r] + bc);
        }
    }
    __syncthreads();

    // ---- coalesced readback: wave w stores its 16 rows (2 iterations) ----
    int nb = blockIdx.x * 64 + w * 16;
    #pragma unroll
    for (int i = 0; i < 2; ++i) {
        int rl = i * 8 + (l >> 3);   // 0..15
        int c = l & 7;               // uint4 chunk within the 64-half row
        int n = nb + rl;
        if (n < N) {
            uint4 val = *reinterpret_cast<const uint4*>(&stw[rl * 72 + c * 8]);
            if (c < 4)
                *reinterpret_cast<uint4*>(U + (size_t)n * 32 + c * 8) = val;
            else
                *reinterpret_cast<uint4*>(V + (size_t)n * 32 + (c - 4) * 8) = val;
        }
    }
}

// ---------------------------------------------------------------------------
// Kernel 2: quad-cooperative edge decode, 4 edges per quad (unchanged; at the
// random-gather byte floor: ~293 MB L2-miss traffic @ ~3.8 TB/s).
// ---------------------------------------------------------------------------
__device__ inline float edge_dot(uint4 uq, uint4 vq, float4 w2a, float4 w2b) {
    float acc = 0.0f;
    float2 uu, vv; float h0, h1;
    uu = h2f(uq.x); vv = h2f(vq.x);
    h0 = uu.x + vv.x; h1 = uu.y + vv.y;
    h0 = (h0 >= 0.0f) ? h0 : LEAKY * h0;
    h1 = (h1 >= 0.0f) ? h1 : LEAKY * h1;
    acc = fmaf(h0, w2a.x, acc); acc = fmaf(h1, w2a.y, acc);
    uu = h2f(uq.y); vv = h2f(vq.y);
    h0 = uu.x + vv.x; h1 = uu.y + vv.y;
    h0 = (h0 >= 0.0f) ? h0 : LEAKY * h0;
    h1 = (h1 >= 0.0f) ? h1 : LEAKY * h1;
    acc = fmaf(h0, w2a.z, acc); acc = fmaf(h1, w2a.w, acc);
    uu = h2f(uq.z); vv = h2f(vq.z);
    h0 = uu.x + vv.x; h1 = uu.y + vv.y;
    h0 = (h0 >= 0.0f) ? h0 : LEAKY * h0;
    h1 = (h1 >= 0.0f) ? h1 : LEAKY * h1;
    acc = fmaf(h0, w2b.x, acc); acc = fmaf(h1, w2b.y, acc);
    uu = h2f(uq.w); vv = h2f(vq.w);
    h0 = uu.x + vv.x; h1 = uu.y + vv.y;
    h0 = (h0 >= 0.0f) ? h0 : LEAKY * h0;
    h1 = (h1 >= 0.0f) ? h1 : LEAKY * h1;
    acc = fmaf(h0, w2b.z, acc); acc = fmaf(h1, w2b.w, acc);
    return acc;
}

__global__ __launch_bounds__(256) void edge_decode_q4(
    const int* __restrict__ idx,
    const __half* __restrict__ U, const __half* __restrict__ V,
    const float* __restrict__ W2, const float* __restrict__ b2,
    float* __restrict__ out, int E)
{
    int t = blockIdx.x * blockDim.x + threadIdx.x;
    int p = t & 3;
    int e0 = t & ~3;
    if (e0 >= E) return;
    int eN = E - 1;
    int ea = min(e0, eN), eb = min(e0 + 1, eN), ec = min(e0 + 2, eN), ed = min(e0 + 3, eN);

    int s0 = idx[ea], s1 = idx[eb], s2 = idx[ec], s3 = idx[ed];
    int d0 = idx[E + ea], d1 = idx[E + eb], d2 = idx[E + ec], d3 = idx[E + ed];

    const uint4* Up = reinterpret_cast<const uint4*>(U);
    const uint4* Vp = reinterpret_cast<const uint4*>(V);
    uint4 u0 = Up[(size_t)s0 * 4 + p];
    uint4 u1 = Up[(size_t)s1 * 4 + p];
    uint4 u2 = Up[(size_t)s2 * 4 + p];
    uint4 u3 = Up[(size_t)s3 * 4 + p];
    uint4 v0 = Vp[(size_t)d0 * 4 + p];
    uint4 v1 = Vp[(size_t)d1 * 4 + p];
    uint4 v2 = Vp[(size_t)d2 * 4 + p];
    uint4 v3 = Vp[(size_t)d3 * 4 + p];

    float4 w2a = *reinterpret_cast<const float4*>(W2 + p * 8);
    float4 w2b = *reinterpret_cast<const float4*>(W2 + p * 8 + 4);

    float a0 = edge_dot(u0, v0, w2a, w2b);
    float a1 = edge_dot(u1, v1, w2a, w2b);
    float a2 = edge_dot(u2, v2, w2a, w2b);
    float a3 = edge_dot(u3, v3, w2a, w2b);

    a0 += __shfl_xor(a0, 1); a0 += __shfl_xor(a0, 2);
    a1 += __shfl_xor(a1, 1); a1 += __shfl_xor(a1, 2);
    a2 += __shfl_xor(a2, 1); a2 += __shfl_xor(a2, 2);
    a3 += __shfl_xor(a3, 1); a3 += __shfl_xor(a3, 2);

    float r = (p == 0) ? a0 : (p == 1) ? a1 : (p == 2) ? a2 : a3;
    r = fast_tanh(r + b2[0]);
    int eo = e0 + p;
    if (eo < E) out[eo] = r;
}

// ---------------------------------------------------------------------------
// Fallback if the workspace is too small for U/V.
// ---------------------------------------------------------------------------
__global__ __launch_bounds__(256) void edge_mlp_f32(
    const float* __restrict__ z, const int* __restrict__ idx,
    const float* __restrict__ W1, const float* __restrict__ b1,
    const float* __restrict__ W2, const float* __restrict__ b2,
    float* __restrict__ out, int E)
{
    int e = blockIdx.x * blockDim.x + threadIdx.x;
    if (e >= E) return;
    int s = idx[e];
    int d = idx[E + e];
    const float4* zs = reinterpret_cast<const float4*>(z + (size_t)s * 64);
    const float4* zd = reinterpret_cast<const float4*>(z + (size_t)d * 64);

    float h[32];
    #pragma unroll
    for (int j = 0; j < 32; ++j) h[j] = b1[j];

    #pragma unroll 4
    for (int k4 = 0; k4 < 16; ++k4) {
        float4 a = zs[k4];
        float4 b = zd[k4];
        const float* wa0 = W1 + (4 * k4 + 0) * 32;
        const float* wa1 = W1 + (4 * k4 + 1) * 32;
        const float* wa2 = W1 + (4 * k4 + 2) * 32;
        const float* wa3 = W1 + (4 * k4 + 3) * 32;
        const float* wb0 = W1 + (64 + 4 * k4 + 0) * 32;
        const float* wb1 = W1 + (64 + 4 * k4 + 1) * 32;
        const float* wb2 = W1 + (64 + 4 * k4 + 2) * 32;
        const float* wb3 = W1 + (64 + 4 * k4 + 3) * 32;
        #pragma unroll
        for (int j = 0; j < 32; ++j) {
            float acc = h[j];
            acc = fmaf(a.x, wa0[j], acc);
            acc = fmaf(a.y, wa1[j], acc);
            acc = fmaf(a.z, wa2[j], acc);
            acc = fmaf(a.w, wa3[j], acc);
            acc = fmaf(b.x, wb0[j], acc);
            acc = fmaf(b.y, wb1[j], acc);
            acc = fmaf(b.z, wb2[j], acc);
            acc = fmaf(b.w, wb3[j], acc);
            h[j] = acc;
        }
    }

    float acc = b2[0];
    #pragma unroll
    for (int j = 0; j < 32; ++j) {
        float hv = h[j];
        hv = (hv >= 0.0f) ? hv : LEAKY * hv;
        acc = fmaf(hv, W2[j], acc);
    }
    out[e] = tanhf(acc);
}

extern "C" void kernel_launch(void* const* d_in, const int* in_sizes, int n_in,
                              void* d_out, int out_size, void* d_ws, size_t ws_size,
                              hipStream_t stream) {
    const float* z  = (const float*)d_in[0];
    const int*   idx = (const int*)d_in[1];
    const float* W1 = (const float*)d_in[2];
    const float* b1 = (const float*)d_in[3];
    const float* W2 = (const float*)d_in[4];
    const float* b2 = (const float*)d_in[5];
    float* out = (float*)d_out;

    const int E = out_size;            // 3,200,000
    const int N = in_sizes[0] / 64;    // 100,000 nodes

    size_t need = (size_t)2 * N * 32 * sizeof(__half);  // 12.8 MB
    if (ws_size >= need) {
        __half* U = (__half*)d_ws;
        __half* V = U + (size_t)N * 32;
        const int threads = 256;
        int nblocks_np = (N + 63) / 64;
        node_proj_mfma64<<<nblocks_np, threads, 0, stream>>>(z, W1, b1, U, V, N);
        edge_decode_q4<<<(E + threads - 1) / threads, threads, 0, stream>>>(
            idx, U, V, W2, b2, out, E);
    } else {
        const int threads = 256;
        edge_mlp_f32<<<(E + threads - 1) / threads, threads, 0, stream>>>(
            z, idx, W1, b1, W2, b2, out, E);
    }
}